// Round 8
// baseline (1915.518 us; speedup 1.0000x reference)
//
#include <hip/hip_runtime.h>
#include <hip/hip_bf16.h>
#include <math.h>

// ---------------------------------------------------------------------------
// LSTM_55327768708454:  T=128 B=256 D=512 H=1024 O=1
// Round 8: persistent recurrence, latency-trimmed step:
//  - direct barrier: each block's 128 threads poll all 128 producer flags in
//    parallel (no aggregator/go hops; 4 IC round trips -> 2)
//  - K-loop unroll 16 (deeper load pipelining)
//  - xg prefetched one step ahead (latency off the critical path)
// ---------------------------------------------------------------------------

#define T_STEPS 128
#define BATCH   256
#define DIM     512
#define HID     1024
#define GATES   4096
#define FPAD    32   // ints per flag slot (128B)

typedef __attribute__((ext_vector_type(8))) short short8;
typedef __attribute__((ext_vector_type(4))) float f4;
typedef __attribute__((ext_vector_type(4))) int i4;

__device__ __forceinline__ short f2bf(float f) {
    union { float f; unsigned u; } x; x.f = f;
    unsigned r = (x.u + 0x7fffu + ((x.u >> 16) & 1u)) >> 16;
    return (short)r;
}
__device__ __forceinline__ float bf2f(short s) {
    union { unsigned u; float f; } x; x.u = ((unsigned)(unsigned short)s) << 16;
    return x.f;
}
__device__ __forceinline__ float sigm(float x) { return 1.f / (1.f + __expf(-x)); }
__device__ __forceinline__ float tanh_fast(float x) { return 2.f / (1.f + __expf(-2.f * x)) - 1.f; }

__device__ __forceinline__ void gll16(const void* g, void* l) {
    __builtin_amdgcn_global_load_lds(
        (const __attribute__((address_space(1))) void*)g,
        (__attribute__((address_space(3))) void*)l, 16, 0, 0);
}
__device__ __forceinline__ void store16_wt(void* p, i4 v) {
    asm volatile("global_store_dwordx4 %0, %1, off sc0 sc1"
                 :: "v"(p), "v"(v) : "memory");
}

// ---------------- helpers ----------------
__global__ __launch_bounds__(256) void cvt_f32_bf16(const float* __restrict__ in,
                                                    short* __restrict__ out, int n4) {
    int i = blockIdx.x * 256 + threadIdx.x;
    if (i < n4) {
        float4 v = ((const float4*)in)[i];
        union { short s[4]; long long ll; } r;
        r.s[0] = f2bf(v.x); r.s[1] = f2bf(v.y); r.s[2] = f2bf(v.z); r.s[3] = f2bf(v.w);
        ((long long*)out)[i] = r.ll;
    }
}

// out row r' = hc*4+g  <-  in row g*1024+hc  (W_ih: xg cols gate-packed)
__global__ __launch_bounds__(256) void cvt_permute_rows(const float* __restrict__ in,
                                                        short* __restrict__ out) {
    int r = blockIdx.x;
    int hc = r >> 2, g = r & 3;
    const float* src = in + (size_t)(g * HID + hc) * HID;
    short* dst = out + (size_t)r * HID;
    int c = threadIdx.x * 4;
    float4 v = *(const float4*)&src[c];
    union { short s[4]; long long ll; } p;
    p.s[0] = f2bf(v.x); p.s[1] = f2bf(v.y); p.s[2] = f2bf(v.z); p.s[3] = f2bf(v.w);
    *(long long*)&dst[c] = p.ll;
}

__global__ __launch_bounds__(256) void bias_sum_perm(const float* __restrict__ a,
                                                     const float* __restrict__ b,
                                                     float* __restrict__ o) {
    int r = blockIdx.x * 256 + threadIdx.x;
    int hc = r >> 2, g = r & 3;
    int src = g * HID + hc;
    o[r] = a[src] + b[src];
}

__global__ __launch_bounds__(256) void copy_f32v4(const float* __restrict__ in,
                                                  float* __restrict__ out, int n4) {
    int i = blockIdx.x * 256 + threadIdx.x;
    if (i < n4) ((float4*)out)[i] = ((const float4*)in)[i];
}

__global__ __launch_bounds__(256) void zero_i32(int* __restrict__ p, int n) {
    for (int i = blockIdx.x * 256 + threadIdx.x; i < n; i += gridDim.x * 256)
        p[i] = 0;
}

// ---------------- m97-style bf16 GEMM:  C = A @ B^T + bias, opt relu ----------------
__global__ __launch_bounds__(256) void gemm_bt(const short* __restrict__ A,
                                               const short* __restrict__ B,
                                               const float* __restrict__ bias,
                                               short* __restrict__ C,
                                               int M, int N, int K, int do_relu) {
    __shared__ __align__(16) short As[128 * 32];
    __shared__ __align__(16) short Bs[128 * 32];
    const int tid = threadIdx.x, wave = tid >> 6, lane = tid & 63;
    const int wm = (wave >> 1) * 64, wn = (wave & 1) * 64;
    const int bm = blockIdx.x * 128, bn = blockIdx.y * 128;
    const int sr = lane >> 2, sc = (lane & 3) * 8;

    f4 acc[4][4] = {};

    for (int k0 = 0; k0 < K; k0 += 32) {
        __syncthreads();
#pragma unroll
        for (int j = 0; j < 2; ++j) {
            int c = wave * 2 + j;
            gll16(&A[(size_t)(bm + c * 16 + sr) * K + k0 + sc], &As[c * 512]);
            gll16(&B[(size_t)(bn + c * 16 + sr) * K + k0 + sc], &Bs[c * 512]);
        }
        __syncthreads();
        short8 af[4], bfr[4];
#pragma unroll
        for (int i = 0; i < 4; ++i) {
            af[i]  = *(const short8*)&As[(wm + i * 16 + (lane & 15)) * 32 + (lane >> 4) * 8];
            bfr[i] = *(const short8*)&Bs[(wn + i * 16 + (lane & 15)) * 32 + (lane >> 4) * 8];
        }
#pragma unroll
        for (int i = 0; i < 4; ++i)
#pragma unroll
            for (int j = 0; j < 4; ++j)
                acc[i][j] = __builtin_amdgcn_mfma_f32_16x16x32_bf16(af[i], bfr[j], acc[i][j], 0, 0, 0);
    }

    const int lc = lane & 15, lr = (lane >> 4) * 4;
#pragma unroll
    for (int i = 0; i < 4; ++i) {
#pragma unroll
        for (int j = 0; j < 4; ++j) {
            int col = bn + wn + j * 16 + lc;
            float bv = bias[col];
#pragma unroll
            for (int r = 0; r < 4; ++r) {
                int row = bm + wm + i * 16 + lr + r;
                float v = acc[i][j][r] + bv;
                if (do_relu) v = fmaxf(v, 0.f);
                C[(size_t)row * N + col] = f2bf(v);
            }
        }
    }
}

// ---------------- persistent recurrence over TC steps ----------------
// 512 blocks (2/CU): bg = bx>>7 (64 batch rows), cg = bx&127 (8 h-cols).
__global__ __launch_bounds__(256) void lstm_persist(const short* __restrict__ Whh,
                                                    const short* __restrict__ xgc,
                                                    short* __restrict__ hist,
                                                    float* __restrict__ cf,
                                                    float* __restrict__ hT,
                                                    float* __restrict__ cT,
                                                    int* __restrict__ flags,
                                                    int TC, int last) {
    __shared__ __align__(16) short Bf[32768];   // 64 KB W_hh strip fragments
    __shared__ __align__(16) short Ht[512];     // 1 KB h-tile staging (64 rows x 8 cols)
    const int tid = threadIdx.x, w = tid >> 6, lane = tid & 63;
    const int bg = blockIdx.x >> 7, cg = blockIdx.x & 127;
    const int bb = bg * 64, hc0 = cg * 8;
    const int hcl = lane & 7, gp = (lane >> 3) & 1, q = lane >> 4;

    // ---- fill W_hh strip fragments once ----
#pragma unroll
    for (int i = 0; i < 16; ++i) {
        int p = w * 16 + i;
        int c = p >> 1, t = p & 1;
        gll16(&Whh[(size_t)((t * 2 + gp) * HID + hc0 + hcl) * HID + c * 32 + q * 8],
              &Bf[p * 512]);
    }

    // ---- c-state into registers ----
    const int rowb = bb + w * 16 + q * 4 + gp * 2;       // rows rowb, rowb+1
    float creg[2];
#pragma unroll
    for (int e = 0; e < 2; ++e)
        creg[e] = cf[(size_t)(rowb + e) * HID + hc0 + hcl];

    __syncthreads();   // strip ready

    // prime xg for step 0
    unsigned long long xw[2], xwn[2];
#pragma unroll
    for (int e = 0; e < 2; ++e)
        xw[e] = *(const unsigned long long*)&xgc[(size_t)(0 * BATCH + rowb + e) * GATES
                                                 + (hc0 + hcl) * 4];

    for (int tt = 0; tt < TC; ++tt) {
        // ---- prefetch next step's xg (latency hidden under K-loop+barrier) ----
        if (tt + 1 < TC) {
#pragma unroll
            for (int e = 0; e < 2; ++e)
                xwn[e] = *(const unsigned long long*)&xgc[(size_t)((tt + 1) * BATCH + rowb + e) * GATES
                                                          + (hc0 + hcl) * 4];
        }

        // ---- K-loop: A plain from global, B resident in LDS ----
        const short* aptr = hist + (size_t)tt * BATCH * HID
                          + (size_t)(bb + w * 16 + (lane & 15)) * HID + q * 8;
        f4 acc0 = {}, acc1 = {};
#pragma unroll 16
        for (int c = 0; c < 32; ++c) {
            short8 af = *(const short8*)(aptr + c * 32);
            short8 b0 = *(const short8*)&Bf[(c * 2 + 0) * 512 + lane * 8];
            short8 b1 = *(const short8*)&Bf[(c * 2 + 1) * 512 + lane * 8];
            acc0 = __builtin_amdgcn_mfma_f32_16x16x32_bf16(af, b0, acc0, 0, 0, 0);
            acc1 = __builtin_amdgcn_mfma_f32_16x16x32_bf16(af, b1, acc1, 0, 0, 0);
        }

        // ---- gate exchange across lane^8 ----
        float p0[4], p1[4];
#pragma unroll
        for (int r = 0; r < 4; ++r) {
            p0[r] = __shfl_xor(acc0[r], 8);
            p1[r] = __shfl_xor(acc1[r], 8);
        }

        int glast = last && (tt == TC - 1);
#pragma unroll
        for (int e = 0; e < 2; ++e) {
            int r = gp * 2 + e;
            size_t b = rowb + e;
            float gi = gp ? p0[r] : acc0[r];
            float gf = gp ? acc0[r] : p0[r];
            float gg = gp ? p1[r] : acc1[r];
            float go_ = gp ? acc1[r] : p1[r];
            gi += bf2f((short)(xw[e] & 0xffff));
            gf += bf2f((short)((xw[e] >> 16) & 0xffff));
            gg += bf2f((short)((xw[e] >> 32) & 0xffff));
            go_ += bf2f((short)((xw[e] >> 48) & 0xffff));
            float si = sigm(gi), sf = sigm(gf), tg = tanh_fast(gg), so = sigm(go_);
            float cn = sf * creg[e] + si * tg;
            float hv = so * tanh_fast(cn);
            creg[e] = cn;
            Ht[(w * 16 + q * 4 + gp * 2 + e) * 8 + hcl] = f2bf(hv);
            if (glast) {
                hT[b * HID + hc0 + hcl] = hv;
                cT[b * HID + hc0 + hcl] = cn;
            }
        }
        xw[0] = xwn[0]; xw[1] = xwn[1];
        __syncthreads();   // Ht complete

        // ---- packed 16B write-through h stores (64 rows x 8 cols) ----
        short* hn = hist + (size_t)(tt + 1) * BATCH * HID;
        if (tid < 64)
            store16_wt(&hn[(size_t)(bb + tid) * HID + hc0], *(const i4*)&Ht[tid * 8]);

        // ---- direct barrier: parallel flag stores + all-blocks parallel poll ----
        if (tt < TC - 1) {
            __syncthreads();   // drains vmcnt for the 64 storing threads
            const int base = (tt * 4 + bg) * 128 * FPAD;
            if (tid == 0)
                __hip_atomic_store(&flags[base + cg * FPAD], 1,
                                   __ATOMIC_RELAXED, __HIP_MEMORY_SCOPE_AGENT);
            if (tid < 128) {
                while (__hip_atomic_load(&flags[base + tid * FPAD],
                                         __ATOMIC_RELAXED, __HIP_MEMORY_SCOPE_AGENT) == 0)
                    __builtin_amdgcn_s_sleep(1);
            }
            __syncthreads();
        }
    }

    // ---- write back c-state for next chunk ----
#pragma unroll
    for (int e = 0; e < 2; ++e)
        cf[(size_t)(rowb + e) * HID + hc0 + hcl] = creg[e];
}

// ---------------- output head over one chunk of h history ----------------
__global__ __launch_bounds__(256) void out_head(const short* __restrict__ hs,
                                                const float* __restrict__ Wout,
                                                const float* __restrict__ bout,
                                                float* __restrict__ out) {
    int row = blockIdx.x * 4 + (threadIdx.x >> 6);
    int lane = threadIdx.x & 63;
    const int* h2 = (const int*)(hs + ((size_t)row + BATCH) * HID);
    const float2* w2 = (const float2*)Wout;
    float s = 0.f;
#pragma unroll
    for (int j = 0; j < 8; ++j) {
        int idx = lane + 64 * j;
        int pk = h2[idx];
        float2 wv = w2[idx];
        union { unsigned u; float f; } lo, hi;
        lo.u = ((unsigned)pk) << 16;
        hi.u = ((unsigned)pk) & 0xffff0000u;
        s += lo.f * wv.x + hi.f * wv.y;
    }
#pragma unroll
    for (int off = 32; off; off >>= 1) s += __shfl_down(s, off);
    if (lane == 0) out[row] = s + bout[0];
}

// ---------------------------------------------------------------------------
extern "C" void kernel_launch(void* const* d_in, const int* in_sizes, int n_in,
                              void* d_out, int out_size, void* d_ws, size_t ws_size,
                              hipStream_t stream) {
    const float* inputs = (const float*)d_in[0];
    const float* h0     = (const float*)d_in[1];
    const float* c0     = (const float*)d_in[2];
    const float* W1     = (const float*)d_in[3];
    const float* b1     = (const float*)d_in[4];
    const float* W_ih   = (const float*)d_in[5];
    const float* W_hh   = (const float*)d_in[6];
    const float* b_ih   = (const float*)d_in[7];
    const float* b_hh   = (const float*)d_in[8];
    const float* W_out  = (const float*)d_in[9];
    const float* b_out  = (const float*)d_in[10];

    float* out = (float*)d_out;
    float* hT  = out + (size_t)T_STEPS * BATCH;
    float* cT  = hT + (size_t)BATCH * HID;

    char* base = (char*)d_ws;
    size_t off = 0;
    auto alloc = [&](size_t bytes) -> char* {
        char* q = base + off;
        off += (bytes + 255) & ~(size_t)255;
        return q;
    };
    short* W1b   = (short*)alloc((size_t)HID * DIM * 2);
    short* Wihb  = (short*)alloc((size_t)GATES * HID * 2);      // row-permuted
    short* Whhb  = (short*)alloc((size_t)GATES * HID * 2);      // plain layout
    float* biasf = (float*)alloc((size_t)GATES * 4);            // permuted
    float* cf    = (float*)alloc((size_t)BATCH * HID * 4);
    int*   flags = (int*)alloc((size_t)T_STEPS * 4 * 128 * FPAD * 4);  // 8 MB

    size_t per_t = (size_t)BATCH * (DIM + HID + GATES) * 2 + (size_t)BATCH * HID * 2;
    int TC = 32;
    while (TC > 1 && off + (size_t)TC * per_t + (size_t)BATCH * HID * 2 + 65536 > ws_size)
        TC >>= 1;

    short* hhist = (short*)alloc((size_t)(TC + 1) * BATCH * HID * 2);
    short* inb_c = (short*)alloc((size_t)TC * BATCH * DIM * 2);
    short* xb_c  = (short*)alloc((size_t)TC * BATCH * HID * 2);
    short* xgb_c = (short*)alloc((size_t)TC * BATCH * GATES * 2);

    // ---- weight prep ----
    cvt_f32_bf16<<<(HID * DIM / 4 + 255) / 256, 256, 0, stream>>>(W1, W1b, HID * DIM / 4);
    cvt_permute_rows<<<GATES, 256, 0, stream>>>(W_ih, Wihb);
    cvt_f32_bf16<<<(GATES * HID / 4 + 255) / 256, 256, 0, stream>>>(W_hh, Whhb, GATES * HID / 4);
    bias_sum_perm<<<GATES / 256, 256, 0, stream>>>(b_ih, b_hh, biasf);
    cvt_f32_bf16<<<(BATCH * HID / 4 + 255) / 256, 256, 0, stream>>>(h0, hhist, BATCH * HID / 4);
    copy_f32v4<<<(BATCH * HID / 4 + 255) / 256, 256, 0, stream>>>(c0, cf, BATCH * HID / 4);

    // ---- chunked pipeline ----
    for (int t0 = 0; t0 < T_STEPS; t0 += TC) {
        int Mc = TC * BATCH;
        int last = (t0 + TC >= T_STEPS);
        cvt_f32_bf16<<<(Mc * DIM / 4 + 255) / 256, 256, 0, stream>>>(
            inputs + (size_t)t0 * BATCH * DIM, inb_c, Mc * DIM / 4);
        gemm_bt<<<dim3(Mc / 128, HID / 128), 256, 0, stream>>>(
            inb_c, W1b, b1, xb_c, Mc, HID, DIM, 1);
        gemm_bt<<<dim3(Mc / 128, GATES / 128), 256, 0, stream>>>(
            xb_c, Wihb, biasf, xgb_c, Mc, GATES, HID, 0);

        zero_i32<<<256, 256, 0, stream>>>(flags, TC * 4 * 128 * FPAD);
        lstm_persist<<<512, 256, 0, stream>>>(Whhb, xgb_c, hhist, cf,
                                              hT, cT, flags, TC, last);

        out_head<<<TC * BATCH / 4, 256, 0, stream>>>(hhist, W_out, b_out,
                                                     out + (size_t)t0 * BATCH);
        copy_f32v4<<<(BATCH * HID * 2 / 16 + 255) / 256, 256, 0, stream>>>(
            (const float*)(hhist + (size_t)TC * BATCH * HID), (float*)hhist,
            BATCH * HID * 2 / 16);
    }
}

// Round 9
// 1592.678 us; speedup vs baseline: 1.2027x; 1.2027x over previous
//
#include <hip/hip_runtime.h>
#include <hip/hip_bf16.h>
#include <math.h>

// ---------------------------------------------------------------------------
// LSTM_55327768708454:  T=128 B=256 D=512 H=1024 O=1
// Round 9: persistent recurrence with LINE-OWNED blocked h layout:
//   hist[slot][slice(=k/8)][b][8] -- producer block writes 8 FULL 128B lines
//   (r7/r8 wrote 16B sectors of lines shared by 8 blocks across XCDs; IC
//   partial-line merge was the hidden ~5us/step). Barrier = r7 aggregator
//   (lowest-congestion measured); flags indexed by absolute t, zeroed once.
// ---------------------------------------------------------------------------

#define T_STEPS 128
#define BATCH   256
#define DIM     512
#define HID     1024
#define GATES   4096
#define FPAD    32   // ints per flag slot (128B)

typedef __attribute__((ext_vector_type(8))) short short8;
typedef __attribute__((ext_vector_type(4))) float f4;
typedef __attribute__((ext_vector_type(4))) int i4;

__device__ __forceinline__ short f2bf(float f) {
    union { float f; unsigned u; } x; x.f = f;
    unsigned r = (x.u + 0x7fffu + ((x.u >> 16) & 1u)) >> 16;
    return (short)r;
}
__device__ __forceinline__ float bf2f(short s) {
    union { unsigned u; float f; } x; x.u = ((unsigned)(unsigned short)s) << 16;
    return x.f;
}
__device__ __forceinline__ float sigm(float x) { return 1.f / (1.f + __expf(-x)); }
__device__ __forceinline__ float tanh_fast(float x) { return 2.f / (1.f + __expf(-2.f * x)) - 1.f; }

__device__ __forceinline__ void gll16(const void* g, void* l) {
    __builtin_amdgcn_global_load_lds(
        (const __attribute__((address_space(1))) void*)g,
        (__attribute__((address_space(3))) void*)l, 16, 0, 0);
}
__device__ __forceinline__ void store16_wt(void* p, i4 v) {
    asm volatile("global_store_dwordx4 %0, %1, off sc0 sc1"
                 :: "v"(p), "v"(v) : "memory");
}

// ---------------- helpers ----------------
__global__ __launch_bounds__(256) void cvt_f32_bf16(const float* __restrict__ in,
                                                    short* __restrict__ out, int n4) {
    int i = blockIdx.x * 256 + threadIdx.x;
    if (i < n4) {
        float4 v = ((const float4*)in)[i];
        union { short s[4]; long long ll; } r;
        r.s[0] = f2bf(v.x); r.s[1] = f2bf(v.y); r.s[2] = f2bf(v.z); r.s[3] = f2bf(v.w);
        ((long long*)out)[i] = r.ll;
    }
}

// h0 fp32 (B,H) -> blocked bf16 [slice][b][8]
__global__ __launch_bounds__(256) void cvt_h0_blocked(const float* __restrict__ h0,
                                                      short* __restrict__ dst) {
    int b = blockIdx.x, k0 = threadIdx.x * 4;
    float4 v = *(const float4*)&h0[(size_t)b * HID + k0];
    union { short s[4]; long long ll; } p;
    p.s[0] = f2bf(v.x); p.s[1] = f2bf(v.y); p.s[2] = f2bf(v.z); p.s[3] = f2bf(v.w);
    *(long long*)&dst[(k0 >> 3) * (BATCH * 8) + b * 8 + (k0 & 7)] = p.ll;
}

// out row r' = hc*4+g  <-  in row g*1024+hc  (W_ih: xg cols gate-packed)
__global__ __launch_bounds__(256) void cvt_permute_rows(const float* __restrict__ in,
                                                        short* __restrict__ out) {
    int r = blockIdx.x;
    int hc = r >> 2, g = r & 3;
    const float* src = in + (size_t)(g * HID + hc) * HID;
    short* dst = out + (size_t)r * HID;
    int c = threadIdx.x * 4;
    float4 v = *(const float4*)&src[c];
    union { short s[4]; long long ll; } p;
    p.s[0] = f2bf(v.x); p.s[1] = f2bf(v.y); p.s[2] = f2bf(v.z); p.s[3] = f2bf(v.w);
    *(long long*)&dst[c] = p.ll;
}

__global__ __launch_bounds__(256) void bias_sum_perm(const float* __restrict__ a,
                                                     const float* __restrict__ b,
                                                     float* __restrict__ o) {
    int r = blockIdx.x * 256 + threadIdx.x;
    int hc = r >> 2, g = r & 3;
    int src = g * HID + hc;
    o[r] = a[src] + b[src];
}

__global__ __launch_bounds__(256) void copy_f32v4(const float* __restrict__ in,
                                                  float* __restrict__ out, int n4) {
    int i = blockIdx.x * 256 + threadIdx.x;
    if (i < n4) ((float4*)out)[i] = ((const float4*)in)[i];
}

__global__ __launch_bounds__(256) void zero_i32(int* __restrict__ p, int n) {
    for (int i = blockIdx.x * 256 + threadIdx.x; i < n; i += gridDim.x * 256)
        p[i] = 0;
}

// ---------------- m97-style bf16 GEMM:  C = A @ B^T + bias, opt relu ----------------
__global__ __launch_bounds__(256) void gemm_bt(const short* __restrict__ A,
                                               const short* __restrict__ B,
                                               const float* __restrict__ bias,
                                               short* __restrict__ C,
                                               int M, int N, int K, int do_relu) {
    __shared__ __align__(16) short As[128 * 32];
    __shared__ __align__(16) short Bs[128 * 32];
    const int tid = threadIdx.x, wave = tid >> 6, lane = tid & 63;
    const int wm = (wave >> 1) * 64, wn = (wave & 1) * 64;
    const int bm = blockIdx.x * 128, bn = blockIdx.y * 128;
    const int sr = lane >> 2, sc = (lane & 3) * 8;

    f4 acc[4][4] = {};

    for (int k0 = 0; k0 < K; k0 += 32) {
        __syncthreads();
#pragma unroll
        for (int j = 0; j < 2; ++j) {
            int c = wave * 2 + j;
            gll16(&A[(size_t)(bm + c * 16 + sr) * K + k0 + sc], &As[c * 512]);
            gll16(&B[(size_t)(bn + c * 16 + sr) * K + k0 + sc], &Bs[c * 512]);
        }
        __syncthreads();
        short8 af[4], bfr[4];
#pragma unroll
        for (int i = 0; i < 4; ++i) {
            af[i]  = *(const short8*)&As[(wm + i * 16 + (lane & 15)) * 32 + (lane >> 4) * 8];
            bfr[i] = *(const short8*)&Bs[(wn + i * 16 + (lane & 15)) * 32 + (lane >> 4) * 8];
        }
#pragma unroll
        for (int i = 0; i < 4; ++i)
#pragma unroll
            for (int j = 0; j < 4; ++j)
                acc[i][j] = __builtin_amdgcn_mfma_f32_16x16x32_bf16(af[i], bfr[j], acc[i][j], 0, 0, 0);
    }

    const int lc = lane & 15, lr = (lane >> 4) * 4;
#pragma unroll
    for (int i = 0; i < 4; ++i) {
#pragma unroll
        for (int j = 0; j < 4; ++j) {
            int col = bn + wn + j * 16 + lc;
            float bv = bias[col];
#pragma unroll
            for (int r = 0; r < 4; ++r) {
                int row = bm + wm + i * 16 + lr + r;
                float v = acc[i][j][r] + bv;
                if (do_relu) v = fmaxf(v, 0.f);
                C[(size_t)row * N + col] = f2bf(v);
            }
        }
    }
}

// ---------------- persistent recurrence over TC steps ----------------
// 512 blocks (2/CU): bg = bx>>7 (64 batch rows), cg = bx&127 (8 h-cols).
// hist slots are BLOCKED: [slice(=k/8)][b][8], slice cg owned by block (.,cg).
__global__ __launch_bounds__(256) void lstm_persist(const short* __restrict__ Whh,
                                                    const short* __restrict__ xgc,
                                                    short* __restrict__ hist,
                                                    float* __restrict__ cf,
                                                    float* __restrict__ hT,
                                                    float* __restrict__ cT,
                                                    int* __restrict__ flags,
                                                    int* __restrict__ go,
                                                    int TC, int last) {
    __shared__ __align__(16) short Bf[32768];   // 64 KB W_hh strip fragments
    __shared__ __align__(16) short Ht[512];     // 1 KB h-tile staging (64 rows x 8 cols)
    const int tid = threadIdx.x, w = tid >> 6, lane = tid & 63;
    const int bg = blockIdx.x >> 7, cg = blockIdx.x & 127;
    const int bb = bg * 64, hc0 = cg * 8;
    const int hcl = lane & 7, gp = (lane >> 3) & 1, q = lane >> 4;

    // ---- fill W_hh strip fragments once ----
#pragma unroll
    for (int i = 0; i < 16; ++i) {
        int p = w * 16 + i;
        int c = p >> 1, t = p & 1;
        gll16(&Whh[(size_t)((t * 2 + gp) * HID + hc0 + hcl) * HID + c * 32 + q * 8],
              &Bf[p * 512]);
    }

    // ---- c-state into registers ----
    const int rowb = bb + w * 16 + q * 4 + gp * 2;       // rows rowb, rowb+1
    float creg[2];
#pragma unroll
    for (int e = 0; e < 2; ++e)
        creg[e] = cf[(size_t)(rowb + e) * HID + hc0 + hcl];

    __syncthreads();   // strip ready

    // prime xg for step 0
    unsigned long long xw[2], xwn[2];
#pragma unroll
    for (int e = 0; e < 2; ++e)
        xw[e] = *(const unsigned long long*)&xgc[(size_t)(rowb + e) * GATES
                                                 + (hc0 + hcl) * 4];

    for (int tt = 0; tt < TC; ++tt) {
        // ---- prefetch next step's xg ----
        if (tt + 1 < TC) {
#pragma unroll
            for (int e = 0; e < 2; ++e)
                xwn[e] = *(const unsigned long long*)&xgc[(size_t)((tt + 1) * BATCH + rowb + e) * GATES
                                                          + (hc0 + hcl) * 4];
        }

        // ---- K-loop: A from blocked hist (slice = c*4+q), B resident in LDS ----
        const short* abase = hist + (size_t)tt * BATCH * HID
                           + (size_t)q * (BATCH * 8) + (size_t)(bb + w * 16 + (lane & 15)) * 8;
        f4 acc0 = {}, acc1 = {};
#pragma unroll 8
        for (int c = 0; c < 32; ++c) {
            short8 af = *(const short8*)(abase + (size_t)c * 4 * (BATCH * 8));
            short8 b0 = *(const short8*)&Bf[(c * 2 + 0) * 512 + lane * 8];
            short8 b1 = *(const short8*)&Bf[(c * 2 + 1) * 512 + lane * 8];
            acc0 = __builtin_amdgcn_mfma_f32_16x16x32_bf16(af, b0, acc0, 0, 0, 0);
            acc1 = __builtin_amdgcn_mfma_f32_16x16x32_bf16(af, b1, acc1, 0, 0, 0);
        }

        // ---- gate exchange across lane^8 ----
        float p0[4], p1[4];
#pragma unroll
        for (int r = 0; r < 4; ++r) {
            p0[r] = __shfl_xor(acc0[r], 8);
            p1[r] = __shfl_xor(acc1[r], 8);
        }

        int glast = last && (tt == TC - 1);
#pragma unroll
        for (int e = 0; e < 2; ++e) {
            int r = gp * 2 + e;
            size_t b = rowb + e;
            float gi = gp ? p0[r] : acc0[r];
            float gf = gp ? acc0[r] : p0[r];
            float gg = gp ? p1[r] : acc1[r];
            float go_ = gp ? acc1[r] : p1[r];
            gi += bf2f((short)(xw[e] & 0xffff));
            gf += bf2f((short)((xw[e] >> 16) & 0xffff));
            gg += bf2f((short)((xw[e] >> 32) & 0xffff));
            go_ += bf2f((short)((xw[e] >> 48) & 0xffff));
            float si = sigm(gi), sf = sigm(gf), tg = tanh_fast(gg), so = sigm(go_);
            float cn = sf * creg[e] + si * tg;
            float hv = so * tanh_fast(cn);
            creg[e] = cn;
            Ht[(w * 16 + q * 4 + gp * 2 + e) * 8 + hcl] = f2bf(hv);
            if (glast) {
                hT[b * HID + hc0 + hcl] = hv;
                cT[b * HID + hc0 + hcl] = cn;
            }
        }
        xw[0] = xwn[0]; xw[1] = xwn[1];
        __syncthreads();   // Ht complete

        // ---- packed h stores: 64 x 16B CONTIGUOUS (8 full lines, single writer) ----
        short* hn = hist + (size_t)(tt + 1) * BATCH * HID
                  + (size_t)cg * (BATCH * 8) + (size_t)bb * 8;
        if (tid < 64)
            store16_wt(&hn[tid * 8], *(const i4*)&Ht[tid * 8]);

        // ---- aggregator barrier (r7 topology, lowest congestion) ----
        if (tt < TC - 1) {
            __syncthreads();   // drains vmcnt for the 64 storing threads
            const int base = (tt * 4 + bg) * 128 * FPAD;
            if (tid == 0)
                __hip_atomic_store(&flags[base + cg * FPAD], 1,
                                   __ATOMIC_RELAXED, __HIP_MEMORY_SCOPE_AGENT);
            if (cg == 0) {
                if (tid < 128) {
                    while (__hip_atomic_load(&flags[base + tid * FPAD],
                                             __ATOMIC_RELAXED, __HIP_MEMORY_SCOPE_AGENT) == 0)
                        __builtin_amdgcn_s_sleep(1);
                }
                __syncthreads();
                if (tid == 0)
                    __hip_atomic_store(&go[(tt * 4 + bg) * FPAD], 1,
                                       __ATOMIC_RELAXED, __HIP_MEMORY_SCOPE_AGENT);
            } else {
                if (tid == 0) {
                    while (__hip_atomic_load(&go[(tt * 4 + bg) * FPAD],
                                             __ATOMIC_RELAXED, __HIP_MEMORY_SCOPE_AGENT) == 0)
                        __builtin_amdgcn_s_sleep(1);
                }
                __syncthreads();
            }
        }
    }

    // ---- write back c-state for next chunk ----
#pragma unroll
    for (int e = 0; e < 2; ++e)
        cf[(size_t)(rowb + e) * HID + hc0 + hcl] = creg[e];
}

// ---------------- output head over one chunk of h history (blocked layout) ----------------
__global__ __launch_bounds__(256) void out_head(const short* __restrict__ hs,
                                                const float* __restrict__ Wout,
                                                const float* __restrict__ bout,
                                                float* __restrict__ out) {
    int row = blockIdx.x * 4 + (threadIdx.x >> 6);   // tt*256 + b
    int lane = threadIdx.x & 63;
    int tt = row >> 8, b = row & 255;
    const short* sb = hs + (size_t)(tt + 1) * BATCH * HID + b * 8;   // slot tt+1
    const float2* w2 = (const float2*)Wout;
    float s = 0.f;
#pragma unroll
    for (int j = 0; j < 8; ++j) {
        int m = j * 64 + lane;                       // pair index 0..511, k=2m
        int pk = *(const int*)&sb[(size_t)(m >> 2) * (BATCH * 8) + 2 * (m & 3)];
        float2 wv = w2[m];
        union { unsigned u; float f; } lo, hi;
        lo.u = ((unsigned)pk) << 16;
        hi.u = ((unsigned)pk) & 0xffff0000u;
        s += lo.f * wv.x + hi.f * wv.y;
    }
#pragma unroll
    for (int off = 32; off; off >>= 1) s += __shfl_down(s, off);
    if (lane == 0) out[row] = s + bout[0];
}

// ---------------------------------------------------------------------------
extern "C" void kernel_launch(void* const* d_in, const int* in_sizes, int n_in,
                              void* d_out, int out_size, void* d_ws, size_t ws_size,
                              hipStream_t stream) {
    const float* inputs = (const float*)d_in[0];
    const float* h0     = (const float*)d_in[1];
    const float* c0     = (const float*)d_in[2];
    const float* W1     = (const float*)d_in[3];
    const float* b1     = (const float*)d_in[4];
    const float* W_ih   = (const float*)d_in[5];
    const float* W_hh   = (const float*)d_in[6];
    const float* b_ih   = (const float*)d_in[7];
    const float* b_hh   = (const float*)d_in[8];
    const float* W_out  = (const float*)d_in[9];
    const float* b_out  = (const float*)d_in[10];

    float* out = (float*)d_out;
    float* hT  = out + (size_t)T_STEPS * BATCH;
    float* cT  = hT + (size_t)BATCH * HID;

    char* base = (char*)d_ws;
    size_t off = 0;
    auto alloc = [&](size_t bytes) -> char* {
        char* q = base + off;
        off += (bytes + 255) & ~(size_t)255;
        return q;
    };
    short* W1b   = (short*)alloc((size_t)HID * DIM * 2);
    short* Wihb  = (short*)alloc((size_t)GATES * HID * 2);      // row-permuted
    short* Whhb  = (short*)alloc((size_t)GATES * HID * 2);      // plain layout
    float* biasf = (float*)alloc((size_t)GATES * 4);            // permuted
    float* cf    = (float*)alloc((size_t)BATCH * HID * 4);
    int*   flags = (int*)alloc((size_t)T_STEPS * 4 * 128 * FPAD * 4);  // 8 MB
    int*   go    = (int*)alloc((size_t)T_STEPS * 4 * FPAD * 4);        // 64 KB

    size_t per_t = (size_t)BATCH * (DIM + HID + GATES) * 2 + (size_t)BATCH * HID * 2;
    int TC = 32;
    while (TC > 1 && off + (size_t)TC * per_t + (size_t)BATCH * HID * 2 + 65536 > ws_size)
        TC >>= 1;

    short* hhist = (short*)alloc((size_t)(TC + 1) * BATCH * HID * 2);
    short* inb_c = (short*)alloc((size_t)TC * BATCH * DIM * 2);
    short* xb_c  = (short*)alloc((size_t)TC * BATCH * HID * 2);
    short* xgb_c = (short*)alloc((size_t)TC * BATCH * GATES * 2);

    // ---- weight prep + flag zero (flags indexed by absolute t -> zero once) ----
    cvt_f32_bf16<<<(HID * DIM / 4 + 255) / 256, 256, 0, stream>>>(W1, W1b, HID * DIM / 4);
    cvt_permute_rows<<<GATES, 256, 0, stream>>>(W_ih, Wihb);
    cvt_f32_bf16<<<(GATES * HID / 4 + 255) / 256, 256, 0, stream>>>(W_hh, Whhb, GATES * HID / 4);
    bias_sum_perm<<<GATES / 256, 256, 0, stream>>>(b_ih, b_hh, biasf);
    cvt_h0_blocked<<<BATCH, 256, 0, stream>>>(h0, hhist);
    copy_f32v4<<<(BATCH * HID / 4 + 255) / 256, 256, 0, stream>>>(c0, cf, BATCH * HID / 4);
    zero_i32<<<512, 256, 0, stream>>>(flags, T_STEPS * 4 * 128 * FPAD + T_STEPS * 4 * FPAD);

    // ---- chunked pipeline ----
    for (int t0 = 0; t0 < T_STEPS; t0 += TC) {
        int Mc = TC * BATCH;
        int last = (t0 + TC >= T_STEPS);
        cvt_f32_bf16<<<(Mc * DIM / 4 + 255) / 256, 256, 0, stream>>>(
            inputs + (size_t)t0 * BATCH * DIM, inb_c, Mc * DIM / 4);
        gemm_bt<<<dim3(Mc / 128, HID / 128), 256, 0, stream>>>(
            inb_c, W1b, b1, xb_c, Mc, HID, DIM, 1);
        gemm_bt<<<dim3(Mc / 128, GATES / 128), 256, 0, stream>>>(
            xb_c, Wihb, biasf, xgb_c, Mc, GATES, HID, 0);

        lstm_persist<<<512, 256, 0, stream>>>(Whhb, xgb_c, hhist, cf, hT, cT,
                                              flags + (size_t)t0 * 4 * 128 * FPAD,
                                              go + (size_t)t0 * 4 * FPAD,
                                              TC, last);

        out_head<<<TC * BATCH / 4, 256, 0, stream>>>(hhist, W_out, b_out,
                                                     out + (size_t)t0 * BATCH);
        copy_f32v4<<<(BATCH * HID * 2 / 16 + 255) / 256, 256, 0, stream>>>(
            (const float*)(hhist + (size_t)TC * BATCH * HID), (float*)hhist,
            BATCH * HID * 2 / 16);
    }
}